// Round 1
// baseline (323.179 us; speedup 1.0000x reference)
//
#include <hip/hip_runtime.h>
#include <hip/hip_bf16.h>

#define NNODES 50000
#define IN_DIM 256
#define OUT_DIM 128
#define SCALE 1.8f
#define ALPHA 0.15f
#define NB_SCAN 196  // ceil(50000/256)

typedef unsigned short ushort_t;
typedef __attribute__((ext_vector_type(8))) _Float16 f16x8;
typedef __attribute__((ext_vector_type(4))) float f32x4;

// ---------------- helpers ----------------

__device__ __forceinline__ unsigned short f2bf_rne(float f) {
    unsigned int u = __float_as_uint(f);
    unsigned int r = u + 0x7fffu + ((u >> 16) & 1u);  // round-to-nearest-even
    return (unsigned short)(r >> 16);
}

__device__ __forceinline__ float2 bf2_to_f2(unsigned int p) {
    float2 f;
    f.x = __uint_as_float(p << 16);
    f.y = __uint_as_float(p & 0xffff0000u);
    return f;
}

__device__ __forceinline__ unsigned int f2_to_bf2(float x, float y) {
    return (unsigned int)f2bf_rne(x) | ((unsigned int)f2bf_rne(y) << 16);
}

__device__ __forceinline__ unsigned short f2h(float f) {
    _Float16 h = (_Float16)f;  // RNE
    return *(unsigned short*)&h;
}

// ---------------- degree count ----------------

__global__ void deg_scatter_kernel(const int* __restrict__ col, int* __restrict__ cnt, int E) {
    int e = blockIdx.x * blockDim.x + threadIdx.x;
    if (e < E) atomicAdd(&cnt[col[e]], 1);
}

// ---------------- W -> fp16 ----------------

__global__ void wcvt_kernel(const float* __restrict__ W, ushort_t* __restrict__ Whf) {
    int i = blockIdx.x * blockDim.x + threadIdx.x;
    if (i < OUT_DIM * IN_DIM) Whf[i] = f2h(W[i]);
}

// ---------------- exclusive scan (3-pass) over cnt; fused per-node coefficients ----------------
// dinv = rsqrt(deg+1); q = (1-a)*dinv^2 (round-1 state coeff);
// gr = ((1-a)*dinv, a/dinv) (round-2 output coeffs).

__global__ void scan_pass1(const int* __restrict__ cnt, int* __restrict__ part) {
    __shared__ int sd[256];
    int t = threadIdx.x;
    int i = blockIdx.x * 256 + t;
    sd[t] = (i < NNODES) ? cnt[i] : 0;
    __syncthreads();
    for (int s = 128; s > 0; s >>= 1) {
        if (t < s) sd[t] += sd[t + s];
        __syncthreads();
    }
    if (t == 0) part[blockIdx.x] = sd[0];
}

__global__ void scan_pass2(int* __restrict__ part) {
    __shared__ int s[256];
    int t = threadIdx.x;
    int v = (t < NB_SCAN) ? part[t] : 0;
    s[t] = v;
    __syncthreads();
    for (int o = 1; o < 256; o <<= 1) {
        int u = (t >= o) ? s[t - o] : 0;
        __syncthreads();
        s[t] += u;
        __syncthreads();
    }
    if (t < NB_SCAN) part[t] = (t == 0) ? 0 : s[t - 1];
}

__global__ void scan_pass3(const int* __restrict__ cnt, const int* __restrict__ part,
                           int* __restrict__ off, int* __restrict__ cur,
                           float* __restrict__ dinv, float* __restrict__ q,
                           float2* __restrict__ gr, int E) {
    __shared__ int s[256];
    int t = threadIdx.x;
    int i = blockIdx.x * 256 + t;
    int v = (i < NNODES) ? cnt[i] : 0;
    s[t] = v;
    __syncthreads();
    for (int o = 1; o < 256; o <<= 1) {
        int u = (t >= o) ? s[t - o] : 0;
        __syncthreads();
        s[t] += u;
        __syncthreads();
    }
    int excl = part[blockIdx.x] + ((t == 0) ? 0 : s[t - 1]);
    if (i < NNODES) {
        off[i] = excl;
        cur[i] = excl;
        float deg = (float)(v + 1);
        float d = rsqrtf(deg);
        dinv[i] = d;
        q[i] = (1.0f - ALPHA) * d * d;
        gr[i] = make_float2((1.0f - ALPHA) * d, ALPHA * sqrtf(deg));  // a/dinv = a*sqrt(deg)
    }
    if (i == NNODES - 1) off[NNODES] = E;
}

// single scattered 4B store per edge (R8: csr_w eliminated algebraically)
__global__ void csr_fill_kernel(const int* __restrict__ row, const int* __restrict__ col,
                                int* __restrict__ cur, int* __restrict__ csr_row, int E) {
    int e = blockIdx.x * blockDim.x + threadIdx.x;
    if (e < E) {
        int c = col[e];
        int p = atomicAdd(&cur[c], 1);
        csr_row[p] = row[e];
    }
}

// ---------------- MFMA GEMM + bias + L2-normalize (pure fp16 inputs) ----------------
// Writes s0 = bf16(dinv * normalize(xW^T+b) * SCALE) -- the dinv-scaled propagation
// state (dinv folded into the per-row scale for free).
// State layout is CHUNKED for the propagation: s0[chunk][node][32] bf16,
// chunk = dim>>5 == wv, offset = j*16 + c. (3.2 MB per chunk -> fits per-XCD L2.)
// C/D layout: col = lane&15, row = (lane>>4)*4 + reg  [m89-verified].
// A layout:  A[m = lane&15][k = (lane>>4)*8 + j]      [m120-verified].

#define XPAD 264  // 256 + 8 halfs; row stride 528 B (16B-aligned)

__global__ void __launch_bounds__(256, 4) gemm_norm_kernel(
        const float* __restrict__ x, const ushort_t* __restrict__ Whf,
        const float* __restrict__ b, const float* __restrict__ dinv,
        ushort_t* __restrict__ s0b) {
    __shared__ __align__(16) ushort_t xh[64][XPAD];

    const int t = threadIdx.x;
    const int wv = t >> 6;
    const int lane = t & 63;
    const int q = lane >> 4;     // quad 0..3
    const int c = lane & 15;
    const int rowBase = blockIdx.x * 64;

    // ---- W fragment preload (loop-invariant, 64 VGPRs; latency buried under staging) ----
    f16x8 wf[2][8];
    float bias[2];
    #pragma unroll
    for (int j = 0; j < 2; ++j) {
        const size_t base = (size_t)((2 * wv + j) * 16 + c) * IN_DIM + q * 8;
        #pragma unroll
        for (int kt = 0; kt < 8; ++kt)
            wf[j][kt] = *(const f16x8*)(Whf + base + kt * 32);
        bias[j] = b[(2 * wv + j) * 16 + c];
    }

    // ---- stage x (64 rows x 256 k), fp32 -> fp16 ----
    #pragma unroll
    for (int it = 0; it < 16; ++it) {
        int s = it * 256 + t;       // float4 slot
        int r = s >> 6;             // row 0..63
        int ks = (s & 63) * 4;      // k 0..252
        int grow = rowBase + r;
        float4 v = make_float4(0.f, 0.f, 0.f, 0.f);
        if (grow < NNODES) v = *(const float4*)(x + (size_t)grow * IN_DIM + ks);
        uint2 p;
        p.x = (unsigned int)f2h(v.x) | ((unsigned int)f2h(v.y) << 16);
        p.y = (unsigned int)f2h(v.z) | ((unsigned int)f2h(v.w) << 16);
        *(uint2*)&xh[r][ks] = p;
    }
    __syncthreads();

    // ---- MFMA main loop: only LDS reads + MFMAs ----
    f32x4 acc[4][2];
    #pragma unroll
    for (int m = 0; m < 4; ++m)
        #pragma unroll
        for (int j = 0; j < 2; ++j) {
            acc[m][j][0] = bias[j]; acc[m][j][1] = bias[j];
            acc[m][j][2] = bias[j]; acc[m][j][3] = bias[j];
        }

    #pragma unroll
    for (int kt = 0; kt < 8; ++kt) {
        const int kb = kt * 32 + q * 8;
        #pragma unroll
        for (int m = 0; m < 4; ++m) {
            f16x8 a = *(const f16x8*)&xh[m * 16 + c][kb];
            #pragma unroll
            for (int j = 0; j < 2; ++j)
                acc[m][j] = __builtin_amdgcn_mfma_f32_16x16x32_f16(a, wf[j][kt], acc[m][j], 0, 0, 0);
        }
    }

    // ---- row L2-norm: butterfly over 16 c-lanes, then cross-wave LDS reduce ----
    float psum[4][4];
    #pragma unroll
    for (int m = 0; m < 4; ++m)
        #pragma unroll
        for (int r = 0; r < 4; ++r)
            psum[m][r] = acc[m][0][r] * acc[m][0][r] + acc[m][1][r] * acc[m][1][r];
    #pragma unroll
    for (int mask = 1; mask < 16; mask <<= 1)
        #pragma unroll
        for (int m = 0; m < 4; ++m)
            #pragma unroll
            for (int r = 0; r < 4; ++r)
                psum[m][r] += __shfl_xor(psum[m][r], mask);

    __syncthreads();  // done reading xh; reuse as reduction scratch
    float* red = (float*)&xh[0][0];       // red[row*8 + wv], 64*8 floats
    float* scl = red + 64 * 8;            // scl[row], 64 floats
    if (c == 0) {
        #pragma unroll
        for (int m = 0; m < 4; ++m)
            #pragma unroll
            for (int r = 0; r < 4; ++r)
                red[(m * 16 + q * 4 + r) * 8 + wv] = psum[m][r];
    }
    __syncthreads();
    if (t < 64) {
        float s = red[t * 8 + 0] + red[t * 8 + 1] + red[t * 8 + 2] + red[t * 8 + 3];
        // fold dinv into the scale: state s0 = dinv * h  (OOB dinv read is harmless)
        scl[t] = dinv[rowBase + t] * SCALE / fmaxf(sqrtf(s), 1e-12f);
    }
    __syncthreads();

    // ---- store s0 (bf16 state, CHUNKED layout [4][N][32]) ----
    #pragma unroll
    for (int m = 0; m < 4; ++m) {
        #pragma unroll
        for (int r = 0; r < 4; ++r) {
            int lrow = m * 16 + q * 4 + r;
            int grow = rowBase + lrow;
            if (grow < NNODES) {
                float sc = scl[lrow];
                #pragma unroll
                for (int j = 0; j < 2; ++j) {
                    float o = acc[m][j][r] * sc;
                    // global dim = (2*wv+j)*16 + c -> chunk = wv, off = j*16+c
                    s0b[((size_t)wv * NNODES + grow) * 32 + j * 16 + c] = f2bf_rne(o);
                }
            }
        }
    }
}

// ---------------- gather propagation: CHUNKED wave-per-node ----------------
// Feature dim split into 4 chunks of 32 dims (16 u32 of bf16x2 per node-chunk row).
// Per-chunk state = 3.2 MB -> fits per-XCD L2 (4 MB); chunk is blockIdx.y (slow
// dispatch dim) so all XCDs stream through one chunk at a time -> random gathers
// become L2 hits.
// Wave = 1 node x 1 chunk; the 4 sixteen-lane quarters process 4 edges in
// parallel (64 B each), reduced at the end with two shfl_xor.
// acctot = sum_in s[r] + s[c]
// Round 1 (FINAL=0, s == s0): s1[c] = q[c]*acctot + ALPHA*s0[c]        -> bf16
// Round 2 (FINAL=1):          out[c] = gr.x*acctot + gr.y*s0[c]        -> fp32

#define CHUNK_U32 16   // 32 dims = 16 u32 per node per chunk
#define NCHUNK 4

template <int FINAL>
__global__ void __launch_bounds__(256) gather_kernel(
        const int* __restrict__ off, const int* __restrict__ csr_row,
        const float* __restrict__ q, const float2* __restrict__ gr,
        const unsigned int* __restrict__ sin, const unsigned int* __restrict__ s0,
        unsigned int* __restrict__ sout_b, float* __restrict__ out_f) {
    const int wv = threadIdx.x >> 6;
    const int lane = threadIdx.x & 63;
    const int qd = lane >> 4;     // quarter 0..3: which edge of the 4-batch
    const int d = lane & 15;      // u32 index within the chunk row
    const int chunk = blockIdx.y;
    const int c = blockIdx.x * 4 + wv;  // gridDim.x*4 == NNODES exactly

    const unsigned int* __restrict__ sin_c = sin + (size_t)chunk * (NNODES * CHUNK_U32);

    const int s = off[c];
    const int e = off[c + 1];

    float2 acc = make_float2(0.f, 0.f);

    for (int base = s; base < e; base += 64) {
        int n = e - base;
        if (n > 64) n = 64;
        int idx = 0;
        if (lane < n) idx = csr_row[base + lane];
        for (int j = 0; j < n; j += 4) {
            int r = __shfl(idx, j + qd);
            if (j + qd < n) {
                float2 v = bf2_to_f2(sin_c[(size_t)r * CHUNK_U32 + d]);
                acc.x += v.x;
                acc.y += v.y;
            }
        }
    }

    // fold the 4 quarters
    acc.x += __shfl_xor(acc.x, 16);
    acc.y += __shfl_xor(acc.y, 16);
    acc.x += __shfl_xor(acc.x, 32);
    acc.y += __shfl_xor(acc.y, 32);

    if (qd == 0) {
        // self term + epilogue on lanes 0..15
        float2 zc = bf2_to_f2(sin_c[(size_t)c * CHUNK_U32 + d]);
        acc.x += zc.x;
        acc.y += zc.y;
        if (FINAL) {
            const unsigned int* __restrict__ s0_c =
                s0 + (size_t)chunk * (NNODES * CHUNK_U32);
            float2 z0 = bf2_to_f2(s0_c[(size_t)c * CHUNK_U32 + d]);
            float2 g = gr[c];
            float ox = g.x * acc.x + g.y * z0.x;
            float oy = g.x * acc.y + g.y * z0.y;
            // out[node][128] f32; float2 slot = c*64 + chunk*16 + d
            ((float2*)out_f)[(size_t)c * 64 + chunk * 16 + d] = make_float2(ox, oy);
        } else {
            unsigned int* __restrict__ sout_c =
                sout_b + (size_t)chunk * (NNODES * CHUNK_U32);
            float qc = q[c];
            float ox = qc * acc.x + ALPHA * zc.x;
            float oy = qc * acc.y + ALPHA * zc.y;
            sout_c[(size_t)c * CHUNK_U32 + d] = f2_to_bf2(ox, oy);
        }
    }
}

extern "C" void kernel_launch(void* const* d_in, const int* in_sizes, int n_in,
                              void* d_out, int out_size, void* d_ws, size_t ws_size,
                              hipStream_t stream) {
    const float* x  = (const float*)d_in[0];
    const int*   ei = (const int*)d_in[1];
    const float* W  = (const float*)d_in[2];
    const float* b  = (const float*)d_in[3];
    float* out = (float*)d_out;

    int E = in_sizes[1] / 2;
    const int* row = ei;       // sources
    const int* col = ei + E;   // targets

    // workspace layout
    float*  dinv = (float*)d_ws;                        // 50048
    float*  q    = dinv + 50048;                        // 50048
    float2* gr   = (float2*)(q + 50048);                // 50048 float2
    unsigned int* s0b = (unsigned int*)(gr + 50048);    // 3.2M u32 (bf16x2, [4][N][16])
    unsigned int* s1b = s0b + (size_t)NNODES * 64;      // 3.2M u32
    int*   cnt   = (int*)(s1b + (size_t)NNODES * 64);   // 50048
    int*   off   = cnt + 50048;                         // 50112 (N+1 used)
    int*   cur   = off + 50112;                         // 50048
    int*   part  = cur + 50048;                         // 256
    int*   csr_row = part + 256;                        // E
    ushort_t* Whf  = (ushort_t*)(csr_row + ((E + 63) & ~63)); // 32768

    hipMemsetAsync(cnt, 0, NNODES * sizeof(int), stream);
    deg_scatter_kernel<<<(E + 255) / 256, 256, 0, stream>>>(col, cnt, E);
    wcvt_kernel<<<(OUT_DIM * IN_DIM + 255) / 256, 256, 0, stream>>>(W, Whf);

    scan_pass1<<<NB_SCAN, 256, 0, stream>>>(cnt, part);
    scan_pass2<<<1, 256, 0, stream>>>(part);
    scan_pass3<<<NB_SCAN, 256, 0, stream>>>(cnt, part, off, cur, dinv, q, gr, E);
    csr_fill_kernel<<<(E + 255) / 256, 256, 0, stream>>>(row, col, cur, csr_row, E);

    gemm_norm_kernel<<<(NNODES + 63) / 64, 256, 0, stream>>>(x, Whf, b, dinv, (ushort_t*)s0b);

    dim3 ggrid(NNODES / 4, NCHUNK);
    gather_kernel<0><<<ggrid, 256, 0, stream>>>(off, csr_row, q, gr, s0b, s0b, s1b, nullptr);
    gather_kernel<1><<<ggrid, 256, 0, stream>>>(off, csr_row, q, gr, s1b, s0b, nullptr, out);
}

// Round 3
// 232.273 us; speedup vs baseline: 1.3914x; 1.3914x over previous
//
#include <hip/hip_runtime.h>
#include <hip/hip_bf16.h>

#define NNODES 50000
#define IN_DIM 256
#define OUT_DIM 128
#define SCALE 1.8f
#define ALPHA 0.15f
#define NB_SCAN 196  // ceil(50000/256)

typedef unsigned short ushort_t;
typedef __attribute__((ext_vector_type(8))) _Float16 f16x8;
typedef __attribute__((ext_vector_type(4))) float f32x4;

// ---------------- helpers ----------------

__device__ __forceinline__ unsigned short f2bf_rne(float f) {
    unsigned int u = __float_as_uint(f);
    unsigned int r = u + 0x7fffu + ((u >> 16) & 1u);  // round-to-nearest-even
    return (unsigned short)(r >> 16);
}

__device__ __forceinline__ float2 bf2_to_f2(unsigned int p) {
    float2 f;
    f.x = __uint_as_float(p << 16);
    f.y = __uint_as_float(p & 0xffff0000u);
    return f;
}

__device__ __forceinline__ unsigned int f2_to_bf2(float x, float y) {
    return (unsigned int)f2bf_rne(x) | ((unsigned int)f2bf_rne(y) << 16);
}

__device__ __forceinline__ unsigned short f2h(float f) {
    _Float16 h = (_Float16)f;  // RNE
    return *(unsigned short*)&h;
}

// ---------------- degree count ----------------

__global__ void deg_scatter_kernel(const int* __restrict__ col, int* __restrict__ cnt, int E) {
    int e = blockIdx.x * blockDim.x + threadIdx.x;
    if (e < E) atomicAdd(&cnt[col[e]], 1);
}

// ---------------- W -> fp16 ----------------

__global__ void wcvt_kernel(const float* __restrict__ W, ushort_t* __restrict__ Whf) {
    int i = blockIdx.x * blockDim.x + threadIdx.x;
    if (i < OUT_DIM * IN_DIM) Whf[i] = f2h(W[i]);
}

// ---------------- exclusive scan (3-pass) over cnt; fused per-node coefficients ----------------
// dinv = rsqrt(deg+1); q = (1-a)*dinv^2 (round-1 state coeff);
// gr = ((1-a)*dinv, a/dinv) (round-2 output coeffs).

__global__ void scan_pass1(const int* __restrict__ cnt, int* __restrict__ part) {
    __shared__ int sd[256];
    int t = threadIdx.x;
    int i = blockIdx.x * 256 + t;
    sd[t] = (i < NNODES) ? cnt[i] : 0;
    __syncthreads();
    for (int s = 128; s > 0; s >>= 1) {
        if (t < s) sd[t] += sd[t + s];
        __syncthreads();
    }
    if (t == 0) part[blockIdx.x] = sd[0];
}

__global__ void scan_pass2(int* __restrict__ part) {
    __shared__ int s[256];
    int t = threadIdx.x;
    int v = (t < NB_SCAN) ? part[t] : 0;
    s[t] = v;
    __syncthreads();
    for (int o = 1; o < 256; o <<= 1) {
        int u = (t >= o) ? s[t - o] : 0;
        __syncthreads();
        s[t] += u;
        __syncthreads();
    }
    if (t < NB_SCAN) part[t] = (t == 0) ? 0 : s[t - 1];
}

__global__ void scan_pass3(const int* __restrict__ cnt, const int* __restrict__ part,
                           int* __restrict__ off, int* __restrict__ cur,
                           float* __restrict__ dinv, float* __restrict__ q,
                           float2* __restrict__ gr, int E) {
    __shared__ int s[256];
    int t = threadIdx.x;
    int i = blockIdx.x * 256 + t;
    int v = (i < NNODES) ? cnt[i] : 0;
    s[t] = v;
    __syncthreads();
    for (int o = 1; o < 256; o <<= 1) {
        int u = (t >= o) ? s[t - o] : 0;
        __syncthreads();
        s[t] += u;
        __syncthreads();
    }
    int excl = part[blockIdx.x] + ((t == 0) ? 0 : s[t - 1]);
    if (i < NNODES) {
        off[i] = excl;
        cur[i] = excl;
        float deg = (float)(v + 1);
        float d = rsqrtf(deg);
        dinv[i] = d;
        q[i] = (1.0f - ALPHA) * d * d;
        gr[i] = make_float2((1.0f - ALPHA) * d, ALPHA * sqrtf(deg));  // a/dinv = a*sqrt(deg)
    }
    if (i == NNODES - 1) off[NNODES] = E;
}

// single scattered 4B store per edge (R8: csr_w eliminated algebraically)
__global__ void csr_fill_kernel(const int* __restrict__ row, const int* __restrict__ col,
                                int* __restrict__ cur, int* __restrict__ csr_row, int E) {
    int e = blockIdx.x * blockDim.x + threadIdx.x;
    if (e < E) {
        int c = col[e];
        int p = atomicAdd(&cur[c], 1);
        csr_row[p] = row[e];
    }
}

// ---------------- MFMA GEMM + bias + L2-normalize (pure fp16 inputs) ----------------
// Writes s0 = bf16(dinv * normalize(xW^T+b) * SCALE) -- the dinv-scaled propagation
// state (dinv folded into the per-row scale for free). Layout [N][128] bf16:
// full 256-B rows so the random gather uses whole cache lines (chunked layout
// regressed: half-line waste + no L2 residency).
// C/D layout: col = lane&15, row = (lane>>4)*4 + reg  [m89-verified].
// A layout:  A[m = lane&15][k = (lane>>4)*8 + j]      [m120-verified].

#define XPAD 264  // 256 + 8 halfs; row stride 528 B (16B-aligned)

__global__ void __launch_bounds__(256, 4) gemm_norm_kernel(
        const float* __restrict__ x, const ushort_t* __restrict__ Whf,
        const float* __restrict__ b, const float* __restrict__ dinv,
        ushort_t* __restrict__ s0b) {
    __shared__ __align__(16) ushort_t xh[64][XPAD];

    const int t = threadIdx.x;
    const int wv = t >> 6;
    const int lane = t & 63;
    const int q = lane >> 4;     // quad 0..3
    const int c = lane & 15;
    const int rowBase = blockIdx.x * 64;

    // ---- W fragment preload (loop-invariant, 64 VGPRs; latency buried under staging) ----
    f16x8 wf[2][8];
    float bias[2];
    #pragma unroll
    for (int j = 0; j < 2; ++j) {
        const size_t base = (size_t)((2 * wv + j) * 16 + c) * IN_DIM + q * 8;
        #pragma unroll
        for (int kt = 0; kt < 8; ++kt)
            wf[j][kt] = *(const f16x8*)(Whf + base + kt * 32);
        bias[j] = b[(2 * wv + j) * 16 + c];
    }

    // ---- stage x (64 rows x 256 k), fp32 -> fp16 ----
    #pragma unroll
    for (int it = 0; it < 16; ++it) {
        int s = it * 256 + t;       // float4 slot
        int r = s >> 6;             // row 0..63
        int ks = (s & 63) * 4;      // k 0..252
        int grow = rowBase + r;
        float4 v = make_float4(0.f, 0.f, 0.f, 0.f);
        if (grow < NNODES) v = *(const float4*)(x + (size_t)grow * IN_DIM + ks);
        uint2 p;
        p.x = (unsigned int)f2h(v.x) | ((unsigned int)f2h(v.y) << 16);
        p.y = (unsigned int)f2h(v.z) | ((unsigned int)f2h(v.w) << 16);
        *(uint2*)&xh[r][ks] = p;
    }
    __syncthreads();

    // ---- MFMA main loop: only LDS reads + MFMAs ----
    f32x4 acc[4][2];
    #pragma unroll
    for (int m = 0; m < 4; ++m)
        #pragma unroll
        for (int j = 0; j < 2; ++j) {
            acc[m][j][0] = bias[j]; acc[m][j][1] = bias[j];
            acc[m][j][2] = bias[j]; acc[m][j][3] = bias[j];
        }

    #pragma unroll
    for (int kt = 0; kt < 8; ++kt) {
        const int kb = kt * 32 + q * 8;
        #pragma unroll
        for (int m = 0; m < 4; ++m) {
            f16x8 a = *(const f16x8*)&xh[m * 16 + c][kb];
            #pragma unroll
            for (int j = 0; j < 2; ++j)
                acc[m][j] = __builtin_amdgcn_mfma_f32_16x16x32_f16(a, wf[j][kt], acc[m][j], 0, 0, 0);
        }
    }

    // ---- row L2-norm: butterfly over 16 c-lanes, then cross-wave LDS reduce ----
    float psum[4][4];
    #pragma unroll
    for (int m = 0; m < 4; ++m)
        #pragma unroll
        for (int r = 0; r < 4; ++r)
            psum[m][r] = acc[m][0][r] * acc[m][0][r] + acc[m][1][r] * acc[m][1][r];
    #pragma unroll
    for (int mask = 1; mask < 16; mask <<= 1)
        #pragma unroll
        for (int m = 0; m < 4; ++m)
            #pragma unroll
            for (int r = 0; r < 4; ++r)
                psum[m][r] += __shfl_xor(psum[m][r], mask);

    __syncthreads();  // done reading xh; reuse as reduction scratch
    float* red = (float*)&xh[0][0];       // red[row*8 + wv], 64*8 floats
    float* scl = red + 64 * 8;            // scl[row], 64 floats
    if (c == 0) {
        #pragma unroll
        for (int m = 0; m < 4; ++m)
            #pragma unroll
            for (int r = 0; r < 4; ++r)
                red[(m * 16 + q * 4 + r) * 8 + wv] = psum[m][r];
    }
    __syncthreads();
    if (t < 64) {
        float s = red[t * 8 + 0] + red[t * 8 + 1] + red[t * 8 + 2] + red[t * 8 + 3];
        // fold dinv into the scale: state s0 = dinv * h  (OOB dinv read is harmless)
        scl[t] = dinv[rowBase + t] * SCALE / fmaxf(sqrtf(s), 1e-12f);
    }
    __syncthreads();

    // ---- store s0 (bf16 state, [N][128]) ----
    #pragma unroll
    for (int m = 0; m < 4; ++m) {
        #pragma unroll
        for (int r = 0; r < 4; ++r) {
            int lrow = m * 16 + q * 4 + r;
            int grow = rowBase + lrow;
            if (grow < NNODES) {
                float sc = scl[lrow];
                #pragma unroll
                for (int j = 0; j < 2; ++j) {
                    float o = acc[m][j][r] * sc;
                    s0b[(size_t)grow * OUT_DIM + (2 * wv + j) * 16 + c] = f2bf_rne(o);
                }
            }
        }
    }
}

// ---------------- gather propagation: wave-per-node, dwordx4 quarters ----------------
// Full 256-B state rows (2 cache lines per edge, fully used; L3-served).
// Each 16-lane quarter owns one edge and loads its row with dwordx4 (16 B/lane):
// 4 edges per wave-instruction, 4x fewer load issues than dword, 2 groups in
// flight (32 B/lane MLP). Quarter partials fold with two shfl_xor; epilogue on
// quarter 0 with vector stores.
// acctot = sum_in s[r] + s[c]
// Round 1 (FINAL=0, s == s0): s1[c] = q[c]*acctot + ALPHA*s0[c]        -> bf16
// Round 2 (FINAL=1):          out[c] = gr.x*acctot + gr.y*s0[c]        -> fp32

__device__ __forceinline__ void acc_row4(float2* a, uint4 v) {
    float2 f0 = bf2_to_f2(v.x), f1 = bf2_to_f2(v.y);
    float2 f2 = bf2_to_f2(v.z), f3 = bf2_to_f2(v.w);
    a[0].x += f0.x; a[0].y += f0.y;
    a[1].x += f1.x; a[1].y += f1.y;
    a[2].x += f2.x; a[2].y += f2.y;
    a[3].x += f3.x; a[3].y += f3.y;
}

template <int FINAL>
__global__ void __launch_bounds__(256) gather_kernel(
        const int* __restrict__ off, const int* __restrict__ csr_row,
        const float* __restrict__ q, const float2* __restrict__ gr,
        const unsigned int* __restrict__ sin, const unsigned int* __restrict__ s0,
        unsigned int* __restrict__ sout_b, float* __restrict__ out_f) {
    const int wv = threadIdx.x >> 6;
    const int lane = threadIdx.x & 63;
    const int qd = lane >> 4;      // quarter 0..3: which edge of the 4-batch
    const int d16 = lane & 15;     // dwordx4 slot within the 256-B row
    const int c = blockIdx.x * 4 + wv;  // grid*4 == NNODES exactly

    const int s = off[c];
    const int e = off[c + 1];

    float2 a[4];
    #pragma unroll
    for (int k = 0; k < 4; ++k) a[k] = make_float2(0.f, 0.f);

    for (int base = s; base < e; base += 64) {
        int n = e - base;
        if (n > 64) n = 64;
        int idx = 0;
        if (lane < n) idx = csr_row[base + lane];
        int j = 0;
        for (; j + 8 <= n; j += 8) {
            int r0 = __shfl(idx, j + qd);
            int r1 = __shfl(idx, j + 4 + qd);
            uint4 v0 = *(const uint4*)(sin + (size_t)r0 * 64 + d16 * 4);
            uint4 v1 = *(const uint4*)(sin + (size_t)r1 * 64 + d16 * 4);
            acc_row4(a, v0);
            acc_row4(a, v1);
        }
        for (; j < n; j += 4) {
            int jj = j + qd;
            int r0 = __shfl(idx, (jj < n) ? jj : (n - 1));  // clamped; shuffle executed by all lanes
            if (jj < n) {
                uint4 v0 = *(const uint4*)(sin + (size_t)r0 * 64 + d16 * 4);
                acc_row4(a, v0);
            }
        }
    }

    // fold the 4 quarters (after this, all lanes hold the full sum for their d16 slot)
    #pragma unroll
    for (int k = 0; k < 4; ++k) {
        a[k].x += __shfl_xor(a[k].x, 16);
        a[k].y += __shfl_xor(a[k].y, 16);
        a[k].x += __shfl_xor(a[k].x, 32);
        a[k].y += __shfl_xor(a[k].y, 32);
    }

    if (qd == 0) {
        // self term + epilogue on lanes 0..15
        uint4 zc4 = *(const uint4*)(sin + (size_t)c * 64 + d16 * 4);
        float2 zc[4];
        zc[0] = bf2_to_f2(zc4.x); zc[1] = bf2_to_f2(zc4.y);
        zc[2] = bf2_to_f2(zc4.z); zc[3] = bf2_to_f2(zc4.w);
        #pragma unroll
        for (int k = 0; k < 4; ++k) {
            a[k].x += zc[k].x;
            a[k].y += zc[k].y;
        }
        if (FINAL) {
            uint4 z04 = *(const uint4*)(s0 + (size_t)c * 64 + d16 * 4);
            float2 z0[4];
            z0[0] = bf2_to_f2(z04.x); z0[1] = bf2_to_f2(z04.y);
            z0[2] = bf2_to_f2(z04.z); z0[3] = bf2_to_f2(z04.w);
            float2 g = gr[c];
            float4 o0, o1;
            o0.x = g.x * a[0].x + g.y * z0[0].x;
            o0.y = g.x * a[0].y + g.y * z0[0].y;
            o0.z = g.x * a[1].x + g.y * z0[1].x;
            o0.w = g.x * a[1].y + g.y * z0[1].y;
            o1.x = g.x * a[2].x + g.y * z0[2].x;
            o1.y = g.x * a[2].y + g.y * z0[2].y;
            o1.z = g.x * a[3].x + g.y * z0[3].x;
            o1.w = g.x * a[3].y + g.y * z0[3].y;
            float* p = out_f + (size_t)c * 128 + d16 * 8;
            *(float4*)(p) = o0;
            *(float4*)(p + 4) = o1;
        } else {
            float qc = q[c];
            uint4 w;
            w.x = f2_to_bf2(qc * a[0].x + ALPHA * zc[0].x, qc * a[0].y + ALPHA * zc[0].y);
            w.y = f2_to_bf2(qc * a[1].x + ALPHA * zc[1].x, qc * a[1].y + ALPHA * zc[1].y);
            w.z = f2_to_bf2(qc * a[2].x + ALPHA * zc[2].x, qc * a[2].y + ALPHA * zc[2].y);
            w.w = f2_to_bf2(qc * a[3].x + ALPHA * zc[3].x, qc * a[3].y + ALPHA * zc[3].y);
            *(uint4*)(sout_b + (size_t)c * 64 + d16 * 4) = w;
        }
    }
}

extern "C" void kernel_launch(void* const* d_in, const int* in_sizes, int n_in,
                              void* d_out, int out_size, void* d_ws, size_t ws_size,
                              hipStream_t stream) {
    const float* x  = (const float*)d_in[0];
    const int*   ei = (const int*)d_in[1];
    const float* W  = (const float*)d_in[2];
    const float* b  = (const float*)d_in[3];
    float* out = (float*)d_out;

    int E = in_sizes[1] / 2;
    const int* row = ei;       // sources
    const int* col = ei + E;   // targets

    // workspace layout
    float*  dinv = (float*)d_ws;                        // 50048
    float*  q    = dinv + 50048;                        // 50048
    float2* gr   = (float2*)(q + 50048);                // 50048 float2
    unsigned int* s0b = (unsigned int*)(gr + 50048);    // 3.2M u32 (bf16x2, [N][64])
    unsigned int* s1b = s0b + (size_t)NNODES * 64;      // 3.2M u32
    int*   cnt   = (int*)(s1b + (size_t)NNODES * 64);   // 50048
    int*   off   = cnt + 50048;                         // 50112 (N+1 used)
    int*   cur   = off + 50112;                         // 50048
    int*   part  = cur + 50048;                         // 256
    int*   csr_row = part + 256;                        // E
    ushort_t* Whf  = (ushort_t*)(csr_row + ((E + 63) & ~63)); // 32768

    hipMemsetAsync(cnt, 0, NNODES * sizeof(int), stream);
    deg_scatter_kernel<<<(E + 255) / 256, 256, 0, stream>>>(col, cnt, E);
    wcvt_kernel<<<(OUT_DIM * IN_DIM + 255) / 256, 256, 0, stream>>>(W, Whf);

    scan_pass1<<<NB_SCAN, 256, 0, stream>>>(cnt, part);
    scan_pass2<<<1, 256, 0, stream>>>(part);
    scan_pass3<<<NB_SCAN, 256, 0, stream>>>(cnt, part, off, cur, dinv, q, gr, E);
    csr_fill_kernel<<<(E + 255) / 256, 256, 0, stream>>>(row, col, cur, csr_row, E);

    gemm_norm_kernel<<<(NNODES + 63) / 64, 256, 0, stream>>>(x, Whf, b, dinv, (ushort_t*)s0b);

    gather_kernel<0><<<NNODES / 4, 256, 0, stream>>>(off, csr_row, q, gr, s0b, s0b, s1b, nullptr);
    gather_kernel<1><<<NNODES / 4, 256, 0, stream>>>(off, csr_row, q, gr, s1b, s0b, nullptr, out);
}